// Round 1
// baseline (7142.979 us; speedup 1.0000x reference)
//
#include <hip/hip_runtime.h>

#define TT  464
#define HH  256
#define BB  64
#define NWG 64   // persistent LSTM workgroups: 2 batch-groups x 32 feature-groups

using bf16x8 = __attribute__((ext_vector_type(8))) short;   // 8 bf16 (4 VGPRs)
using f32x4  = __attribute__((ext_vector_type(4))) float;   // MFMA accumulator

__device__ __forceinline__ unsigned short f2bf(float x) {
  union { float f; unsigned u; } v; v.f = x;
  unsigned r = v.u + 0x7fffu + ((v.u >> 16) & 1u);   // RNE
  return (unsigned short)(r >> 16);
}

// Device-scope generation barrier for NWG co-resident workgroups.
// cnt counts total arrivals (monotone); gen counts completed barriers.
__device__ __forceinline__ void gsync(int* cnt, int* gen, int target) {
  __threadfence();                 // release our h publishes
  __syncthreads();
  if (threadIdx.x == 0) {
    int prev = __hip_atomic_fetch_add(cnt, 1, __ATOMIC_ACQ_REL, __HIP_MEMORY_SCOPE_AGENT);
    if (prev + 1 == NWG * target) {
      __hip_atomic_fetch_add(gen, 1, __ATOMIC_ACQ_REL, __HIP_MEMORY_SCOPE_AGENT);
    } else {
      while (__hip_atomic_load(gen, __ATOMIC_ACQUIRE, __HIP_MEMORY_SCOPE_AGENT) < target)
        __builtin_amdgcn_s_sleep(2);
    }
  }
  __syncthreads();
  __threadfence();                 // acquire: invalidate stale L1/L2 before reading others' h
}

// Persistent LSTM: wg = (bgi: 32 batch rows) x (fgi: 8 hidden units -> 32 gate cols).
// z[32,32] = [x_t | h] @ [W;U]-slice via mfma_f32_16x16x32_bf16; state fp32 in regs.
__global__ __launch_bounds__(256) void lstm_kernel(
    const float* __restrict__ x,      // [64][464][256]
    const float* __restrict__ h0,     // [64][256]
    const float* __restrict__ c0,     // [64][256]
    const float* __restrict__ W,      // [256][1024]
    const float* __restrict__ U,      // [256][1024]
    const float* __restrict__ bias,   // [1024]
    unsigned short* __restrict__ h_bufs, // [2][64][256] bf16 (double-buffered publish)
    unsigned short* __restrict__ seq,    // [64][464][256] bf16
    float* __restrict__ out,             // d_out: [0:16384) core, [16384) hT, [32768) cT
    int* __restrict__ sync_cnt,
    int* __restrict__ sync_gen)
{
  const int tid = threadIdx.x;
  const int wg  = blockIdx.x;
  const int bgi = wg >> 5;          // 0..1
  const int fgi = wg & 31;          // 0..31
  const int wv  = tid >> 6;         // wave 0..3
  const int ln  = tid & 63;
  const int mt  = wv >> 1;          // M-tile (16 rows)
  const int nt  = wv & 1;           // N-tile (16 cols)
  const int l15 = ln & 15;
  const int q   = ln >> 4;

  // pitches padded +8 bf16: row stride = 4 banks -> 2-way (free, G4/m136)
  __shared__ unsigned short Bt[32][520];     // [W;U] slice, n-major, K=512
  __shared__ unsigned short x_lds[32][264];  // x_t slice bf16
  __shared__ float          z_lds[32][36];   // MFMA result exchange

  // Stage combined weights: Bt[n][k]; n = g*8+j -> global col g*256 + fgi*8 + j
  for (int it = 0; it < 64; ++it) {
    int i  = it * 256 + tid;
    int k  = i >> 5;                 // 0..511
    int n  = i & 31;
    int gc = (n >> 3) * 256 + fgi * 8 + (n & 7);
    float wval = (k < 256) ? W[(size_t)k * 1024 + gc] : U[(size_t)(k - 256) * 1024 + gc];
    Bt[n][k] = f2bf(wval);
  }

  // Per-thread owned state: (r_own, j_own) one (batch-row, hidden-unit) pair
  const int r_own = tid >> 3;        // 0..31
  const int j_own = tid & 7;         // 0..7
  const int brow  = bgi * 32 + r_own;
  const int col   = fgi * 8 + j_own;
  float c = c0[brow * HH + col];
  float h = h0[brow * HH + col];
  const float b_i = bias[        col];
  const float b_f = bias[  HH  + col];
  const float b_g = bias[2*HH  + col];
  const float b_o = bias[3*HH  + col];

  h_bufs[brow * HH + col] = f2bf(h);     // publish h0 into buf 0

  // x prefetch mapping: thread -> (row r_own, cols j_own*32 .. +31)
  const int xc0  = j_own * 32;
  const int xrow = brow;
  float4 xr[8];
  {
    const float4* p = (const float4*)(x + ((size_t)xrow * TT + 0) * HH + xc0);
#pragma unroll
    for (int i = 0; i < 8; ++i) xr[i] = p[i];
  }

  int sy = 1;
  gsync(sync_cnt, sync_gen, sy);     // h0 visible everywhere

  for (int t = 0; t < TT; ++t) {
    const int pr  = t & 1;           // read buffer
    const int pwb = pr ^ 1;          // write buffer

    // h A-fragments straight from global (A[m=l15][k=q*8+j] layout)
    bf16x8 hf[8];
    {
      const unsigned short* hb = h_bufs + pr * (BB * HH) + (bgi * 32 + mt * 16 + l15) * HH;
#pragma unroll
      for (int kk = 0; kk < 8; ++kk)
        hf[kk] = *(const bf16x8*)(hb + kk * 32 + q * 8);
    }

    // x[t] (prefetched last iter) -> bf16 -> LDS
    {
      unsigned px[16];
#pragma unroll
      for (int i = 0; i < 8; ++i) {
        px[2*i]   = (unsigned)f2bf(xr[i].x) | ((unsigned)f2bf(xr[i].y) << 16);
        px[2*i+1] = (unsigned)f2bf(xr[i].z) | ((unsigned)f2bf(xr[i].w) << 16);
      }
#pragma unroll
      for (int s = 0; s < 4; ++s) {
        uint4 v = make_uint4(px[4*s], px[4*s+1], px[4*s+2], px[4*s+3]);
        *(uint4*)&x_lds[r_own][xc0 + s * 8] = v;
      }
    }
    // prefetch x[t+1]
    {
      const int tn = (t + 1 < TT) ? (t + 1) : (TT - 1);
      const float4* p = (const float4*)(x + ((size_t)xrow * TT + tn) * HH + xc0);
#pragma unroll
      for (int i = 0; i < 8; ++i) xr[i] = p[i];
    }

    __syncthreads();

    f32x4 acc = {0.f, 0.f, 0.f, 0.f};
#pragma unroll
    for (int kk = 0; kk < 8; ++kk) {      // x @ W part (K 0..255)
      bf16x8 afr = *(const bf16x8*)&x_lds[mt * 16 + l15][kk * 32 + q * 8];
      bf16x8 bfr = *(const bf16x8*)&Bt[nt * 16 + l15][kk * 32 + q * 8];
      acc = __builtin_amdgcn_mfma_f32_16x16x32_bf16(afr, bfr, acc, 0, 0, 0);
    }
#pragma unroll
    for (int kk = 0; kk < 8; ++kk) {      // h @ U part (K 256..511)
      bf16x8 bfr = *(const bf16x8*)&Bt[nt * 16 + l15][256 + kk * 32 + q * 8];
      acc = __builtin_amdgcn_mfma_f32_16x16x32_bf16(hf[kk], bfr, acc, 0, 0, 0);
    }
    // C/D layout: col = lane&15, row = (lane>>4)*4 + reg (m89-verified)
#pragma unroll
    for (int reg = 0; reg < 4; ++reg)
      z_lds[mt * 16 + q * 4 + reg][nt * 16 + l15] = acc[reg];

    __syncthreads();

    // gates: n = g*8 + j  (i:0..7, f:8..15, g:16..23, o:24..31)
    float zi = z_lds[r_own][      j_own] + b_i;
    float zf = z_lds[r_own][ 8 + j_own] + b_f;
    float zg = z_lds[r_own][16 + j_own] + b_g;
    float zo = z_lds[r_own][24 + j_own] + b_o;
    float gi = 1.f / (1.f + __expf(-zi));
    float gf = 1.f / (1.f + __expf(-zf));
    float go = 1.f / (1.f + __expf(-zo));
    float gg = fmaxf(zg, 0.f);
    c = gf * c + gi * gg;
    h = go * fmaxf(c, 0.f);
    unsigned short hb16 = f2bf(h);
    h_bufs[pwb * (BB * HH) + brow * HH + col] = hb16;
    seq[((size_t)brow * TT + t) * HH + col]   = hb16;

    ++sy;
    gsync(sync_cnt, sync_gen, sy);
  }

  out[16384 + brow * HH + col] = h;   // hT fp32 (un-rounded state)
  out[32768 + brow * HH + col] = c;   // cT
}

// Dense partials: wg kb handles t = kb and kb+232; acc[b, 0..255] over K=512.
// Wd streamed once from HBM (4x wave redundancy absorbed by L2).
__global__ __launch_bounds__(256) void dense_partial(
    const unsigned short* __restrict__ seq,  // [64][464][256] bf16
    const float* __restrict__ Wd,            // [118784][256]
    float* __restrict__ part)                // [232][64][256]
{
  const int kb  = blockIdx.x;     // 0..231
  const int tid = threadIdx.x;
  const int wv  = tid >> 6;       // M-tile
  const int ln  = tid & 63;
  const int l15 = ln & 15;
  const int q   = ln >> 4;
  __shared__ unsigned short a_lds[64][264];

  f32x4 acc[16];
#pragma unroll
  for (int i = 0; i < 16; ++i) acc[i] = (f32x4){0.f, 0.f, 0.f, 0.f};

  for (int half = 0; half < 2; ++half) {
    const int t = kb + half * 232;
    __syncthreads();
#pragma unroll
    for (int it = 0; it < 8; ++it) {
      int cidx = it * 256 + tid;           // 0..2047 16B-chunks
      int row  = cidx >> 5;
      int off  = (cidx & 31) * 8;
      *(bf16x8*)&a_lds[row][off] = *(const bf16x8*)(seq + ((size_t)row * TT + t) * HH + off);
    }
    __syncthreads();

    bf16x8 af[8];
#pragma unroll
    for (int kk = 0; kk < 8; ++kk)
      af[kk] = *(const bf16x8*)&a_lds[wv * 16 + l15][kk * 32 + q * 8];

    const float* wdb = Wd + (size_t)t * HH * HH;
    for (int nt2 = 0; nt2 < 16; ++nt2) {
      const int n = nt2 * 16 + l15;
#pragma unroll
      for (int kk = 0; kk < 8; ++kk) {
        bf16x8 bfr;
#pragma unroll
        for (int j = 0; j < 8; ++j) {
          float wval = wdb[(size_t)(kk * 32 + q * 8 + j) * HH + n];
          bfr[j] = (short)f2bf(wval);
        }
        acc[nt2] = __builtin_amdgcn_mfma_f32_16x16x32_bf16(af[kk], bfr, acc[nt2], 0, 0, 0);
      }
    }
  }

  float* pb = part + (size_t)kb * (BB * HH);
#pragma unroll
  for (int nt2 = 0; nt2 < 16; ++nt2)
#pragma unroll
    for (int reg = 0; reg < 4; ++reg)
      pb[(wv * 16 + q * 4 + reg) * HH + nt2 * 16 + l15] = acc[nt2][reg];
}

__global__ __launch_bounds__(256) void dense_reduce(
    const float* __restrict__ part,   // [232][16384]
    const float* __restrict__ bd,     // [256]
    float* __restrict__ out)          // d_out[0:16384)
{
  const int o = blockIdx.x * 256 + threadIdx.x;
  float s0 = 0.f, s1 = 0.f, s2 = 0.f, s3 = 0.f;
  for (int kb = 0; kb < 232; kb += 4) {
    s0 += part[(size_t)(kb    ) * 16384 + o];
    s1 += part[(size_t)(kb + 1) * 16384 + o];
    s2 += part[(size_t)(kb + 2) * 16384 + o];
    s3 += part[(size_t)(kb + 3) * 16384 + o];
  }
  float s = (s0 + s1) + (s2 + s3) + bd[o & 255];
  out[o] = fmaxf(s, 0.f);
}

extern "C" void kernel_launch(void* const* d_in, const int* in_sizes, int n_in,
                              void* d_out, int out_size, void* d_ws, size_t ws_size,
                              hipStream_t stream) {
  const float* x  = (const float*)d_in[0];
  const float* h0 = (const float*)d_in[1];
  const float* c0 = (const float*)d_in[2];
  const float* W  = (const float*)d_in[3];
  const float* U  = (const float*)d_in[4];
  const float* bv = (const float*)d_in[5];
  const float* Wd = (const float*)d_in[6];
  const float* bd = (const float*)d_in[7];
  float* out = (float*)d_out;

  // d_ws layout (poisoned 0xAA each launch; everything below is rewritten):
  //   [0,128)        sync_cnt        (memset to 0 here)
  //   [128,256)      sync_gen
  //   [256, +64KiB)  h_bufs  [2][64][256] bf16
  //   next 15.2 MB   seq     [64][464][256] bf16
  //   next 15.2 MB   part    [232][64][256] fp32     (total ~30.5 MB)
  char* w = (char*)d_ws;
  int* sync_cnt = (int*)w;
  int* sync_gen = (int*)(w + 128);
  unsigned short* h_bufs = (unsigned short*)(w + 256);
  unsigned short* seq    = (unsigned short*)(w + 256 + 2 * BB * HH * 2);
  float* part            = (float*)(w + 256 + 2 * BB * HH * 2 + (size_t)BB * TT * HH * 2);

  hipMemsetAsync(d_ws, 0, 256, stream);   // reset barrier state every launch
  lstm_kernel<<<NWG, 256, 0, stream>>>(x, h0, c0, W, U, bv, h_bufs, seq, out,
                                       sync_cnt, sync_gen);
  dense_partial<<<232, 256, 0, stream>>>(seq, Wd, part);
  dense_reduce<<<64, 256, 0, stream>>>(part, bd, out);
}

// Round 3
// 2334.008 us; speedup vs baseline: 3.0604x; 3.0604x over previous
//
#include <hip/hip_runtime.h>

#define TT  464
#define HH  256
#define BB  64
#define NWG 64   // persistent LSTM workgroups: 2 batch-groups x 32 feature-groups

using bf16x8 = __attribute__((ext_vector_type(8))) short;   // 8 bf16 (4 VGPRs)
using f32x4  = __attribute__((ext_vector_type(4))) float;   // MFMA accumulator

__device__ __forceinline__ unsigned short f2bf(float x) {
  union { float f; unsigned u; } v; v.f = x;
  unsigned r = v.u + 0x7fffu + ((v.u >> 16) & 1u);   // RNE
  return (unsigned short)(r >> 16);
}

// Flag-array barrier wait: all 4 waves poll the 32 flags of this batch-group
// with one relaxed agent-scope load per lane (no RMW, no cache fences).
__device__ __forceinline__ void wait_flags(int* flags, int base, int target) {
  const int ln  = threadIdx.x & 63;
  int* p = &flags[base + (ln & 31)];
  for (;;) {
    int f = __hip_atomic_load(p, __ATOMIC_RELAXED, __HIP_MEMORY_SCOPE_AGENT);
    if (__all(f >= target)) break;
    __builtin_amdgcn_s_sleep(1);
  }
  asm volatile("" ::: "memory");   // compiler barrier: keep h loads below the poll
}

// Persistent LSTM: wg = (bgi: 32 batch rows) x (fgi: 8 hidden units -> 32 gate cols).
// z[32,32] = [x_t | h] @ [W;U]-slice via mfma_f32_16x16x32_bf16; state fp32 in regs.
// Cross-wg h exchange: packed-u32 relaxed agent atomic stores + u64 relaxed agent
// atomic loads (compiler-lowered coherence bits); per-batch-group flag barrier
// (two independent 32-wg groups). Hand-rolled release: publishes are coherent
// stores, so s_waitcnt(0) + flag store suffices (no cache-maintenance fences).
__global__ __launch_bounds__(256) void lstm_kernel(
    const float* __restrict__ x,      // [64][464][256]
    const float* __restrict__ h0,     // [64][256]
    const float* __restrict__ c0,     // [64][256]
    const float* __restrict__ W,      // [256][1024]
    const float* __restrict__ U,      // [256][1024]
    const float* __restrict__ bias,   // [1024]
    unsigned int* __restrict__ h_bufs,   // [2][64][128] u32 (= [2][64][256] bf16)
    unsigned short* __restrict__ seq,    // [64][464][256] bf16
    float* __restrict__ out,             // d_out: [0:16384) core, [16384) hT, [32768) cT
    int* __restrict__ flags)             // [64]
{
  const int tid = threadIdx.x;
  const int wg  = blockIdx.x;
  const int bgi = wg >> 5;          // 0..1
  const int fgi = wg & 31;          // 0..31
  const int wv  = tid >> 6;         // wave 0..3
  const int ln  = tid & 63;
  const int mt  = wv >> 1;          // M-tile (16 rows)
  const int nt  = wv & 1;           // N-tile (16 cols)
  const int l15 = ln & 15;
  const int q   = ln >> 4;

  __shared__ unsigned short Bt[32][520];     // [W;U] slice, n-major, K=512
  __shared__ unsigned short x_lds[32][264];  // x_t slice bf16
  __shared__ float          z_lds[32][36];   // MFMA result exchange

  // Stage combined weights: Bt[n][k]; n = g*8+j -> global col g*256 + fgi*8 + j
  for (int it = 0; it < 64; ++it) {
    int i  = it * 256 + tid;
    int k  = i >> 5;                 // 0..511
    int n  = i & 31;
    int gc = (n >> 3) * 256 + fgi * 8 + (n & 7);
    float wval = (k < 256) ? W[(size_t)k * 1024 + gc] : U[(size_t)(k - 256) * 1024 + gc];
    Bt[n][k] = f2bf(wval);
  }

  // Per-thread owned state: (r_own, j_own) one (batch-row, hidden-unit) pair
  const int r_own = tid >> 3;        // 0..31
  const int j_own = tid & 7;         // 0..7
  const int brow  = bgi * 32 + r_own;
  const int col   = fgi * 8 + j_own;
  float c = c0[brow * HH + col];
  float h = h0[brow * HH + col];
  const float b_i = bias[        col];
  const float b_f = bias[  HH  + col];
  const float b_g = bias[2*HH  + col];
  const float b_o = bias[3*HH  + col];

  // publish h0 into buf 0 (packed pairs, relaxed agent atomics -> coherent stores)
  {
    unsigned short hb16 = f2bf(h);
    unsigned other = (unsigned)(unsigned short)__shfl_xor((int)hb16, 1);
    if (!(tid & 1)) {
      unsigned hpk = (unsigned)hb16 | (other << 16);
      __hip_atomic_store(&h_bufs[brow * 128 + (col >> 1)], hpk,
                         __ATOMIC_RELAXED, __HIP_MEMORY_SCOPE_AGENT);
    }
  }

  // x prefetch mapping: thread -> (row r_own, cols j_own*32 .. +31)
  const int xc0  = j_own * 32;
  float4 xr[8];
  {
    const float4* p = (const float4*)(x + ((size_t)brow * TT + 0) * HH + xc0);
#pragma unroll
    for (int i = 0; i < 8; ++i) xr[i] = p[i];
  }

  __builtin_amdgcn_s_waitcnt(0);
  __syncthreads();
  if (tid == 0)
    __hip_atomic_store(&flags[wg], 1, __ATOMIC_RELAXED, __HIP_MEMORY_SCOPE_AGENT);

  for (int t = 0; t < TT; ++t) {
    const int pr  = t & 1;           // read buffer
    const int pwb = pr ^ 1;          // write buffer

    // x[t] (prefetched last iter) -> bf16 -> LDS
    {
      unsigned px[16];
#pragma unroll
      for (int i = 0; i < 8; ++i) {
        px[2*i]   = (unsigned)f2bf(xr[i].x) | ((unsigned)f2bf(xr[i].y) << 16);
        px[2*i+1] = (unsigned)f2bf(xr[i].z) | ((unsigned)f2bf(xr[i].w) << 16);
      }
#pragma unroll
      for (int s = 0; s < 4; ++s) {
        uint4 v = make_uint4(px[4*s], px[4*s+1], px[4*s+2], px[4*s+3]);
        *(uint4*)&x_lds[r_own][xc0 + s * 8] = v;
      }
    }
    // prefetch x[t+1]
    {
      const int tn = (t + 1 < TT) ? (t + 1) : (TT - 1);
      const float4* p = (const float4*)(x + ((size_t)brow * TT + tn) * HH + xc0);
#pragma unroll
      for (int i = 0; i < 8; ++i) xr[i] = p[i];
    }

    __syncthreads();                 // (A) x_lds ready

    // x @ W half first: no h dependency, hides in barrier wait
    f32x4 acc = {0.f, 0.f, 0.f, 0.f};
#pragma unroll
    for (int kk = 0; kk < 8; ++kk) {
      bf16x8 afr = *(const bf16x8*)&x_lds[mt * 16 + l15][kk * 32 + q * 8];
      bf16x8 bfr = *(const bf16x8*)&Bt[nt * 16 + l15][kk * 32 + q * 8];
      acc = __builtin_amdgcn_mfma_f32_16x16x32_bf16(afr, bfr, acc, 0, 0, 0);
    }

    wait_flags(flags, bgi * 32, t + 1);   // all group wgs published h_t

    // h A-fragments via u64 relaxed agent atomic loads (coherent, no asm).
    // hf[kk] element e = h[row = bgi*32+mt*16+l15][col = kk*32 + q*8 + e]
    bf16x8 hf[8];
    {
      const unsigned long long* hb = (const unsigned long long*)h_bufs
          + (size_t)pr * (BB * HH / 4) + (bgi * 32 + mt * 16 + l15) * (HH / 4) + q * 2;
#pragma unroll
      for (int kk = 0; kk < 8; ++kk) {
        union { unsigned long long u[2]; bf16x8 v; } tmp;
        tmp.u[0] = __hip_atomic_load(hb + kk * 8 + 0, __ATOMIC_RELAXED, __HIP_MEMORY_SCOPE_AGENT);
        tmp.u[1] = __hip_atomic_load(hb + kk * 8 + 1, __ATOMIC_RELAXED, __HIP_MEMORY_SCOPE_AGENT);
        hf[kk] = tmp.v;
      }
    }
#pragma unroll
    for (int kk = 0; kk < 8; ++kk) {      // h @ U part (K 256..511)
      bf16x8 bfr = *(const bf16x8*)&Bt[nt * 16 + l15][256 + kk * 32 + q * 8];
      acc = __builtin_amdgcn_mfma_f32_16x16x32_bf16(hf[kk], bfr, acc, 0, 0, 0);
    }
    // C/D layout: col = lane&15, row = (lane>>4)*4 + reg (m89-verified)
#pragma unroll
    for (int reg = 0; reg < 4; ++reg)
      z_lds[mt * 16 + q * 4 + reg][nt * 16 + l15] = acc[reg];

    __syncthreads();                 // (C) z ready

    // gates: n = g*8 + j  (i:0..7, f:8..15, g:16..23, o:24..31)
    float zi = z_lds[r_own][      j_own] + b_i;
    float zf = z_lds[r_own][ 8 + j_own] + b_f;
    float zg = z_lds[r_own][16 + j_own] + b_g;
    float zo = z_lds[r_own][24 + j_own] + b_o;
    float gi = 1.f / (1.f + __expf(-zi));
    float gf = 1.f / (1.f + __expf(-zf));
    float go = 1.f / (1.f + __expf(-zo));
    float gg = fmaxf(zg, 0.f);
    c = gf * c + gi * gg;
    h = go * fmaxf(c, 0.f);
    unsigned short hb16 = f2bf(h);
    seq[((size_t)brow * TT + t) * HH + col] = hb16;   // plain store (kernel-boundary coherence)

    // publish h_{t+1}: packed u32, relaxed agent atomic (coherent store)
    {
      unsigned other = (unsigned)(unsigned short)__shfl_xor((int)hb16, 1);
      if (!(tid & 1)) {
        unsigned hpk = (unsigned)hb16 | (other << 16);
        __hip_atomic_store(&h_bufs[pwb * (BB * 128) + brow * 128 + (col >> 1)], hpk,
                           __ATOMIC_RELAXED, __HIP_MEMORY_SCOPE_AGENT);
      }
    }
    __builtin_amdgcn_s_waitcnt(0);   // own publishes at coherent point
    __syncthreads();                 // (D) whole wg's publishes drained
    if (tid == 0)
      __hip_atomic_store(&flags[wg], t + 2, __ATOMIC_RELAXED, __HIP_MEMORY_SCOPE_AGENT);
  }

  out[16384 + brow * HH + col] = h;   // hT fp32 (un-rounded state)
  out[32768 + brow * HH + col] = c;   // cT
}

// Dense partials: wg kb handles t = kb and kb+232; K=512 per wg.
// Wd staged via coalesced float4 loads into LDS (aliased with A-tile), read-time bf16.
#define DP_PA 264   // a_lds pitch (shorts)
#define DP_PW 258   // Wf pitch (floats): 258%32=2 -> 2-way on frag reads (free)
__global__ __launch_bounds__(256) void dense_partial(
    const unsigned short* __restrict__ seq,  // [64][464][256] bf16
    const float* __restrict__ Wd,            // [118784][256]
    float* __restrict__ part)                // [232][64][256]
{
  __shared__ __align__(16) char smem[64 * DP_PA * 2];   // 33792 B >= 32*DP_PW*4
  unsigned short* a_lds = (unsigned short*)smem;
  float*          Wf    = (float*)smem;

  const int kb  = blockIdx.x;     // 0..231
  const int tid = threadIdx.x;
  const int wv  = tid >> 6;       // M-tile
  const int ln  = tid & 63;
  const int l15 = ln & 15;
  const int q   = ln >> 4;

  f32x4 acc[16];
#pragma unroll
  for (int i = 0; i < 16; ++i) acc[i] = (f32x4){0.f, 0.f, 0.f, 0.f};

  for (int half = 0; half < 2; ++half) {
    const int t = kb + half * 232;
    __syncthreads();                       // prev chunk's Wf reads done (smem reuse)
#pragma unroll
    for (int it = 0; it < 8; ++it) {       // stage A: seq[0..63][t][:]
      int cidx = it * 256 + tid;
      int row  = cidx >> 5;
      int off  = (cidx & 31) * 8;
      *(bf16x8*)&a_lds[row * DP_PA + off] =
          *(const bf16x8*)(seq + ((size_t)row * TT + t) * HH + off);
    }
    __syncthreads();
    bf16x8 af[8];
#pragma unroll
    for (int kk = 0; kk < 8; ++kk)
      af[kk] = *(const bf16x8*)&a_lds[(wv * 16 + l15) * DP_PA + kk * 32 + q * 8];

    for (int ck = 0; ck < 8; ++ck) {       // K chunks of 32
      __syncthreads();                     // af in regs / prev Wf reads done
#pragma unroll
      for (int it = 0; it < 8; ++it) {     // stage Wf[32][256] fp32, coalesced
        int idx = it * 256 + tid;
        int r   = idx >> 6;
        int c4  = (idx & 63) * 4;
        float4 v = *(const float4*)(Wd + ((size_t)(t * 256 + ck * 32 + r)) * HH + c4);
        *(float2*)&Wf[r * DP_PW + c4]     = make_float2(v.x, v.y);
        *(float2*)&Wf[r * DP_PW + c4 + 2] = make_float2(v.z, v.w);
      }
      __syncthreads();
#pragma unroll
      for (int nt2 = 0; nt2 < 16; ++nt2) {
        const int n = nt2 * 16 + l15;
        bf16x8 bfr;
#pragma unroll
        for (int j = 0; j < 8; ++j)
          bfr[j] = (short)f2bf(Wf[(q * 8 + j) * DP_PW + n]);
        acc[nt2] = __builtin_amdgcn_mfma_f32_16x16x32_bf16(af[ck], bfr, acc[nt2], 0, 0, 0);
      }
    }
  }

  float* pb = part + (size_t)kb * (BB * HH);
#pragma unroll
  for (int nt2 = 0; nt2 < 16; ++nt2)
#pragma unroll
    for (int reg = 0; reg < 4; ++reg)
      pb[(wv * 16 + q * 4 + reg) * HH + nt2 * 16 + l15] = acc[nt2][reg];
}

__global__ __launch_bounds__(256) void dense_reduce(
    const float* __restrict__ part,   // [232][16384]
    const float* __restrict__ bd,     // [256]
    float* __restrict__ out)          // d_out[0:16384)
{
  const int o = blockIdx.x * 256 + threadIdx.x;
  float s0 = 0.f, s1 = 0.f, s2 = 0.f, s3 = 0.f;
  for (int kb = 0; kb < 232; kb += 4) {
    s0 += part[(size_t)(kb    ) * 16384 + o];
    s1 += part[(size_t)(kb + 1) * 16384 + o];
    s2 += part[(size_t)(kb + 2) * 16384 + o];
    s3 += part[(size_t)(kb + 3) * 16384 + o];
  }
  float s = (s0 + s1) + (s2 + s3) + bd[o & 255];
  out[o] = fmaxf(s, 0.f);
}

extern "C" void kernel_launch(void* const* d_in, const int* in_sizes, int n_in,
                              void* d_out, int out_size, void* d_ws, size_t ws_size,
                              hipStream_t stream) {
  const float* x  = (const float*)d_in[0];
  const float* h0 = (const float*)d_in[1];
  const float* c0 = (const float*)d_in[2];
  const float* W  = (const float*)d_in[3];
  const float* U  = (const float*)d_in[4];
  const float* bv = (const float*)d_in[5];
  const float* Wd = (const float*)d_in[6];
  const float* bd = (const float*)d_in[7];
  float* out = (float*)d_out;

  // d_ws layout:
  //   [0,256)        flags[64]       (memset to 0 here)
  //   [256, +64KiB)  h_bufs  [2][64][256] bf16
  //   next 15.2 MB   seq     [64][464][256] bf16
  //   next 15.2 MB   part    [232][64][256] fp32     (total ~30.5 MB)
  char* w = (char*)d_ws;
  int* flags = (int*)w;
  unsigned int*   h_bufs = (unsigned int*)(w + 256);
  unsigned short* seq    = (unsigned short*)(w + 256 + 2 * BB * HH * 2);
  float*          part   = (float*)(w + 256 + 2 * BB * HH * 2 + (size_t)BB * TT * HH * 2);

  hipMemsetAsync(d_ws, 0, 256, stream);   // reset flags every launch
  lstm_kernel<<<NWG, 256, 0, stream>>>(x, h0, c0, W, U, bv, h_bufs, seq, out, flags);
  dense_partial<<<232, 256, 0, stream>>>(seq, Wd, part);
  dense_reduce<<<64, 256, 0, stream>>>(part, bd, out);
}